// Round 1
// baseline (20.162 us; speedup 1.0000x reference)
//
#include <hip/hip_runtime.h>

// Problem constants (match reference)
#define NTOT 512   // N
#define NH   448   // N - K (head rows, identity part)
#define KK   64    // K (solved rows)
#define NL   30688 // strictly-lower entries in last K rows: sum_{i=448}^{511} i
#define DD   16    // domains

// z = F_d eps with F_d = (I-L)^{-1} S  <=>  (I-L) z = S eps  (forward substitution).
// Rows < 448: z_j = eps_j. Rows 448+r:
//   z = s_r*eps_{448+r} + sum_{j<448} Lrow_r[j]*eps_j + sum_{m<r} Lrow_r[448+m]*z_{448+m}
// Lrow_r starts at off_r = 448*r + r*(r-1)/2 in L_emb[dom].
__global__ __launch_bounds__(256)
void fvae_kernel(const float* __restrict__ eps,      // [B,512]
                 const int*   __restrict__ dom_idx,  // [B]
                 const float* __restrict__ L_emb,    // [16, NL]
                 const float* __restrict__ S_emb,    // [16, 64]
                 const float* __restrict__ bias_ns,  // [16, 64]
                 const float* __restrict__ bias_sh,  // [448]
                 float*       __restrict__ out)      // [B,512]
{
    const int b    = blockIdx.x;
    const int tid  = threadIdx.x;
    const int lane = tid & 63;
    const int wave = tid >> 6;

    __shared__ float eps_s[NTOT];
    __shared__ float y_s[KK];

    const int dom = dom_idx[b];
    const float* __restrict__ epsb = eps + (size_t)b * NTOT;
    float*       __restrict__ outb = out + (size_t)b * NTOT;

    // stage eps in LDS (float2 per thread, coalesced)
    {
        float2 v = *reinterpret_cast<const float2*>(epsb + tid * 2);
        eps_s[tid * 2]     = v.x;
        eps_s[tid * 2 + 1] = v.y;
    }
    __syncthreads();

    // head output: z_j = eps_j + bias_shared_j
    for (int j = tid; j < NH; j += 256)
        outb[j] = eps_s[j] + bias_sh[j];

    const float* __restrict__ Ld = L_emb + (size_t)dom * NL;

    // phase 2: y[r] = s_r*eps[448+r] + dot(Lrow_r[0:448], eps[0:448])
    for (int r = wave; r < KK; r += 4) {
        float acc = 0.f;
        if (dom != 0) {
            const int off = r * NH + (r * (r - 1)) / 2;
            const float* __restrict__ Lr = Ld + off;
            #pragma unroll
            for (int k = 0; k < 7; ++k)           // 448 = 7*64, exact
                acc += Lr[lane + 64 * k] * eps_s[lane + 64 * k];
        }
        #pragma unroll
        for (int s = 32; s; s >>= 1)
            acc += __shfl_xor(acc, s);
        if (lane == 0) {
            const float sr = (dom == 0) ? 1.0f : S_emb[dom * KK + r];
            y_s[r] = sr * eps_s[NH + r] + acc;
        }
    }
    __syncthreads();

    // phase 3: 64x64 unit-lower triangular solve, wave 0 (lane m = row m)
    if (wave == 0) {
        const int m   = lane;
        const int off = m * NH + (m * (m - 1)) / 2;
        float t[KK];
        if (dom != 0) {
            #pragma unroll
            for (int r = 0; r < KK; ++r)
                t[r] = (r < m) ? Ld[off + NH + r] : 0.f;  // max idx = NL-1, in bounds
        } else {
            #pragma unroll
            for (int r = 0; r < KK; ++r) t[r] = 0.f;
        }
        float z = y_s[m];
        #pragma unroll
        for (int r = 0; r < KK - 1; ++r) {
            const float zr = __shfl(z, r);  // lane r's z is final by iteration r
            z += t[r] * zr;                 // t[r]==0 for r>=m -> no-op
        }
        outb[NH + m] = z + bias_ns[dom * KK + m];
    }
}

extern "C" void kernel_launch(void* const* d_in, const int* in_sizes, int n_in,
                              void* d_out, int out_size, void* d_ws, size_t ws_size,
                              hipStream_t stream) {
    const float* eps     = (const float*)d_in[0];
    const int*   dom     = (const int*)  d_in[1];
    const float* L_emb   = (const float*)d_in[2];
    const float* S_emb   = (const float*)d_in[3];
    const float* bias_ns = (const float*)d_in[4];
    const float* bias_sh = (const float*)d_in[5];
    float* out = (float*)d_out;

    const int B = in_sizes[0] / NTOT;  // 1024
    fvae_kernel<<<dim3(B), dim3(256), 0, stream>>>(eps, dom, L_emb, S_emb,
                                                   bias_ns, bias_sh, out);
}